// Round 15
// baseline (136.942 us; speedup 1.0000x reference)
//
#include <hip/hip_runtime.h>
#include <hip/hip_bf16.h>
#include <stdint.h>

// KipfMLPGNN: B=32, N=64 nodes, D=128, H=256, L=3 layers.
// Factorizations:
//  - First MLP layer split into per-node sender/receiver halves (k_T, fp16).
//  - Arc blend: agg = Sum_c (1-a)*m0 + Sum_c a*m1 -> phase in grid.z.
// k_edge v15 = v13 (best structure: ci outer, 2 ks-chains) + opaque asm pin
// on the tr[8]/bv[8] hoists: v13's VGPR=52 proved the RA remat'ed them as
// in-loop L1 reloads (~20us of VALU/VMEM overhead). The pin makes in-loop
// uses refer to asm outputs the compiler can't re-derive -> resident.
// Also: k_gather/k_prep/k_arcT fused into k_setup (12 -> 10 launches).

#define NB 32
#define NN 64
#define DD 128
#define HH 256

typedef __attribute__((ext_vector_type(4))) float f32x4;
typedef __attribute__((ext_vector_type(8))) _Float16 f16x8;

__device__ __forceinline__ uint64_t cvt4h(f32x4 v) {
  union { _Float16 h[4]; uint64_t u; } x;
  x.h[0] = (_Float16)v[0]; x.h[1] = (_Float16)v[1];
  x.h[2] = (_Float16)v[2]; x.h[3] = (_Float16)v[3];
  return x.u;
}

// Fused setup: gather E (256 blk) | W1/W2 -> fp16 (192 blk) | arcs^T (512 blk)
__global__ __launch_bounds__(256) void k_setup(const int* __restrict__ x,
                                               const float* __restrict__ table,
                                               float* __restrict__ E,
                                               const float* __restrict__ W1_0,
                                               const float* __restrict__ W1_1,
                                               const float* __restrict__ W2_0,
                                               const float* __restrict__ W2_1,
                                               _Float16* __restrict__ W1fp,
                                               _Float16* __restrict__ W2fp,
                                               const int* __restrict__ arcs,
                                               int* __restrict__ arcsT) {
  int bid = blockIdx.x, t = threadIdx.x;
  if (bid < 256) {
    int i = bid * 256 + t;
    int node = i >> 5;
    ((f32x4*)E)[i] = ((const f32x4*)table)[(size_t)x[node] * 32 + (i & 31)];
  } else if (bid < 448) {
    int tid = (bid - 256) * 256 + t;     // 49152 f32x4 chunks
    const float* src; uint64_t* dst; int off;
    if (tid < 32768) {
      src = (tid < 16384) ? W1_0 : W1_1;
      off = tid & 16383;
      dst = (uint64_t*)W1fp + (tid >> 14) * 16384 + off;
    } else {
      int t2 = tid - 32768;
      src = (t2 < 8192) ? W2_0 : W2_1;
      off = t2 & 8191;
      dst = (uint64_t*)W2fp + (t2 >> 13) * 8192 + off;
    }
    *dst = cvt4h(((const f32x4*)src)[off]);
  } else {
    int i = (bid - 448) * 256 + t;       // 131072
    int b = i >> 12, rc = i & 4095, r = rc >> 6, c = rc & 63;
    arcsT[b * 4096 + c * 64 + r] = arcs[i];
  }
}

// Tfp[node][1024] = [Ts0 | Tr0+b1_0 | Ts1 | Tr1+b1_1]  (fp16)
// grid (8, 64): x = q*2+half, y = 32-node block.
__global__ __launch_bounds__(256) void k_T(const float* __restrict__ E,
                                           const _Float16* __restrict__ W1fp,
                                           const float* __restrict__ b1_0,
                                           const float* __restrict__ b1_1,
                                           _Float16* __restrict__ Tfp) {
  __shared__ char Els[32 * 256];     // 32 nodes x 128 f16, swizzled rows
  int t = threadIdx.x;
  int gi = blockIdx.x;
  int q = gi >> 1;                   // group 0..3
  int hb = (gi & 1) * 128;           // h-half
  int inoff = (q & 1) * 128;         // sender(0) / receiver(128) input half
  int node0 = blockIdx.y * 32;

#pragma unroll
  for (int ii = 0; ii < 4; ++ii) {
    int idx = ii * 256 + t;          // f32x4 chunk: row=idx>>5, ck=idx&31
    int row = idx >> 5, ck = idx & 31;
    f32x4 v = ((const f32x4*)(E + (size_t)node0 * 128))[idx];
    *(uint64_t*)(Els + row * 256 + ((ck * 8) ^ ((row & 7) << 4))) = cvt4h(v);
  }
  __syncthreads();

  int lane = t & 63, w = t >> 6;     // 4 waves, each 32M x 32N
  int col = lane & 15, khi = lane >> 4;

  const _Float16* Wq = W1fp + (q >> 1) * 65536;
  f16x8 bfr[2][4];
#pragma unroll
  for (int nt = 0; nt < 2; ++nt) {
    int n = w * 32 + nt * 16 + col;
#pragma unroll
    for (int ks = 0; ks < 4; ++ks)
      bfr[nt][ks] = *(const f16x8*)(Wq + (hb + n) * 256 + inoff + ks * 32 + khi * 8);
  }

  f32x4 acc[2][2];
  const f32x4 z = {0.f, 0.f, 0.f, 0.f};
#pragma unroll
  for (int mt = 0; mt < 2; ++mt) { acc[mt][0] = z; acc[mt][1] = z; }

#pragma unroll
  for (int ks = 0; ks < 4; ++ks) {
    f16x8 a[2];
#pragma unroll
    for (int mt = 0; mt < 2; ++mt) {
      int c = mt * 16 + col;
      a[mt] = *(const f16x8*)(Els + c * 256 + ((ks * 64 + khi * 16) ^ ((c & 7) << 4)));
    }
#pragma unroll
    for (int mt = 0; mt < 2; ++mt)
#pragma unroll
      for (int nt = 0; nt < 2; ++nt)
        acc[mt][nt] = __builtin_amdgcn_mfma_f32_16x16x32_f16(a[mt], bfr[nt][ks],
                                                             acc[mt][nt], 0, 0, 0);
  }

  const float* b1q = (q >> 1) ? b1_1 : b1_0;
  float bv[2];
#pragma unroll
  for (int nt = 0; nt < 2; ++nt)
    bv[nt] = (q & 1) ? b1q[hb + w * 32 + nt * 16 + col] : 0.f;

#pragma unroll
  for (int mt = 0; mt < 2; ++mt)
#pragma unroll
    for (int nt = 0; nt < 2; ++nt)
#pragma unroll
      for (int j = 0; j < 4; ++j) {
        int node = node0 + mt * 16 + khi * 4 + j;
        int cgl = q * 256 + hb + w * 32 + nt * 16 + col;
        Tfp[(size_t)node * 1024 + cgl] = (_Float16)(acc[mt][nt][j] + bv[nt]);
      }
}

// E += sum_z Sp[z]   (262144 f32 = 65536 f32x4)
__global__ __launch_bounds__(256) void k_sum(float* __restrict__ E,
                                             const float* __restrict__ Sp) {
  int i = blockIdx.x * 256 + threadIdx.x;      // 65536 f32x4 chunks
  f32x4 acc = ((const f32x4*)E)[i];
#pragma unroll
  for (int zz = 0; zz < 8; ++zz)
    acc += ((const f32x4*)Sp)[zz * 65536 + i];
  ((f32x4*)E)[i] = acc;
}

// out[b][d] = E[b][0][d] + sum_z SpL[z][b][d]
__global__ __launch_bounds__(256) void k_out(const float* __restrict__ E,
                                             const float* __restrict__ SpL,
                                             float* __restrict__ out) {
  int i = blockIdx.x * 256 + threadIdx.x;      // 4096
  float acc = E[(size_t)(i >> 7) * (NN * DD) + (i & 127)];
#pragma unroll
  for (int zz = 0; zz < 8; ++zz)
    acc += SpL[zz * 4096 + i];
  out[i] = acc;
}

// k_edge v15: grid (rb, 32, 16). z: p = z>>3, cq = (z>>1)&3, dh = z&1.
// Block = (b, 16 r's, 16 c's, 64 d-half), 256 thr / 4 waves; wave w owns
// d = dh*64 + w*16 + col. ts tile in 8KB LDS; tr[8]/bv[8] hoisted AND pinned
// via opaque asm (blocks RA remat). Per ci: 8 ds_read + pk relu-add +
// 8 MFMA (2 chains), arc blend into Sacc. Plain stores to Sp[p*4+cq].
template <int LAST>
__global__ __launch_bounds__(256) void k_edge(const _Float16* __restrict__ Tfp,
                                              const int* __restrict__ arcsT,
                                              float* __restrict__ Sp,
                                              const _Float16* __restrict__ W2fp,
                                              const float* __restrict__ b2_0,
                                              const float* __restrict__ b2_1) {
  __shared__ _Float16 tsl[16 * 256];   // 8 KB
  int t = threadIdx.x;
  int z = blockIdx.z;
  int p = z >> 3, cq = (z >> 1) & 3, dh = z & 1;
  int b = blockIdx.y;
  int rbase = LAST ? 0 : blockIdx.x * 16;
  int lane = t & 63, w = t >> 6;
  int col = lane & 15, khi = lane >> 4;
  const _Float16* Tb = Tfp + (size_t)b * NN * 1024;

  // stage ts tile: 16 c-rows x 256 k (512 x 16B chunks)
#pragma unroll
  for (int ii = 0; ii < 2; ++ii) {
    int chunk = ii * 256 + t;
    int ci = chunk >> 5, kc = chunk & 31;
    *(f16x8*)(tsl + ci * 256 + kc * 8) =
        *(const f16x8*)(Tb + (cq * 16 + ci) * 1024 + p * 512 + kc * 8);
  }

  // hoist Tr fragments (32 VGPR)
  f16x8 tr[8];
  {
    const _Float16* trp = Tb + (rbase + col) * 1024 + p * 512 + 256 + khi * 8;
#pragma unroll
    for (int ks = 0; ks < 8; ++ks)
      tr[ks] = *(const f16x8*)(trp + ks * 32);
  }
  // hoist W2 fragments for this wave's 16 d-cols (32 VGPR)
  int d = dh * 64 + w * 16 + col;
  const _Float16* W2p = W2fp + p * 32768;
  f16x8 bv[8];
#pragma unroll
  for (int ks = 0; ks < 8; ++ks)
    bv[ks] = *(const f16x8*)(W2p + d * 256 + ks * 32 + khi * 8);
  float b2v = (p ? b2_1 : b2_0)[d];

  // pin the hoists: in-loop uses now reference asm outputs -> no remat
#pragma unroll
  for (int ks = 0; ks < 8; ++ks)
    asm volatile("" : "+v"(tr[ks]), "+v"(bv[ks]));

  __syncthreads();

  f32x4 Sacc = {0.f, 0.f, 0.f, 0.f};
  const f32x4 z4 = {0.f, 0.f, 0.f, 0.f};
  const int* aT = arcsT + (size_t)b * 4096 + rbase + khi * 4;

#pragma unroll 2
  for (int ci = 0; ci < 16; ++ci) {
    const _Float16* tsr = tsl + ci * 256 + khi * 8;
    f32x4 accA = z4, accB = z4;
#pragma unroll
    for (int ks = 0; ks < 8; ks += 2) {
      f16x8 tsa = *(const f16x8*)(tsr + ks * 32);
      f16x8 tsb = *(const f16x8*)(tsr + ks * 32 + 32);
      f16x8 zv = {};
      f16x8 aA = __builtin_elementwise_max(tsa + tr[ks], zv);
      f16x8 aB = __builtin_elementwise_max(tsb + tr[ks + 1], zv);
      accA = __builtin_amdgcn_mfma_f32_16x16x32_f16(aA, bv[ks], accA, 0, 0, 0);
      accB = __builtin_amdgcn_mfma_f32_16x16x32_f16(aB, bv[ks + 1], accB, 0, 0, 0);
    }
    f32x4 acc = accA + accB;

    int c = cq * 16 + ci;
    const int4 av = *(const int4*)(aT + c * 64);
#pragma unroll
    for (int j = 0; j < 4; ++j) {
      int ai = (j == 0) ? av.x : (j == 1) ? av.y : (j == 2) ? av.z : av.w;
      float wgt = p ? (float)ai : 1.0f - (float)ai;
      Sacc[j] = fmaf(wgt, fmaxf(acc[j] + b2v, 0.f), Sacc[j]);
    }
  }

  // store partials: slice s = p*4+cq
  if (LAST) {
    if (khi == 0)
      Sp[(size_t)(p * 4 + cq) * (NB * DD) + b * DD + d] = Sacc[0];
  } else {
    float* Spz = Sp + (size_t)(p * 4 + cq) * (NB * NN * DD);
#pragma unroll
    for (int j = 0; j < 4; ++j) {
      int r = rbase + khi * 4 + j;
      Spz[((size_t)b * NN + r) * DD + d] = Sacc[j];
    }
  }
}

extern "C" void kernel_launch(void* const* d_in, const int* in_sizes, int n_in,
                              void* d_out, int out_size, void* d_ws, size_t ws_size,
                              hipStream_t stream) {
  const int* x       = (const int*)d_in[0];
  const int* arcs    = (const int*)d_in[1];
  const float* table = (const float*)d_in[3];
  const float* W1_0  = (const float*)d_in[4];
  const float* b1_0  = (const float*)d_in[5];
  const float* W2_0  = (const float*)d_in[6];
  const float* b2_0  = (const float*)d_in[7];
  const float* W1_1  = (const float*)d_in[8];
  const float* b1_1  = (const float*)d_in[9];
  const float* W2_1  = (const float*)d_in[10];
  const float* b2_1  = (const float*)d_in[11];
  float* out = (float*)d_out;

  char* ws = (char*)d_ws;
  float* E         = (float*)ws;                                   // 1 MB
  _Float16* Tfp    = (_Float16*)(ws + (1u << 20));                 // 4 MB
  _Float16* W1fp   = (_Float16*)(ws + (5u << 20));                 // 256 KB
  _Float16* W2fp   = (_Float16*)(ws + (5u << 20) + (256u << 10));  // 128 KB
  int* arcsT       = (int*)(ws + (5u << 20) + (384u << 10));       // 512 KB
  float* Sp        = (float*)(ws + (6u << 20));                    // 8 MB
  float* SpL       = (float*)(ws + (14u << 20));                   // 128 KB

  k_setup<<<960, 256, 0, stream>>>(x, table, E, W1_0, W1_1, W2_0, W2_1,
                                   W1fp, W2fp, arcs, arcsT);
  for (int l = 0; l < 3; ++l) {
    k_T<<<dim3(8, 64), 256, 0, stream>>>(E, W1fp, b1_0, b1_1, Tfp);
    if (l == 2) {
      k_edge<1><<<dim3(1, 32, 16), 256, 0, stream>>>(Tfp, arcsT, SpL,
                                                     W2fp, b2_0, b2_1);
      k_out<<<16, 256, 0, stream>>>(E, SpL, out);
    } else {
      k_edge<0><<<dim3(4, 32, 16), 256, 0, stream>>>(Tfp, arcsT, Sp,
                                                     W2fp, b2_0, b2_1);
      k_sum<<<256, 256, 0, stream>>>(E, Sp);
    }
  }
}

// Round 16
// 102.140 us; speedup vs baseline: 1.3407x; 1.3407x over previous
//
#include <hip/hip_runtime.h>
#include <hip/hip_bf16.h>
#include <stdint.h>

// KipfMLPGNN: B=32, N=64 nodes, D=128, H=256, L=3 layers.
// v16 "one kernel per layer": 5 dispatches total (setup, 3x k_fused, out).
//  - E never materialized: layer l node matrix = E0 + Sum(SpA) [+ Sum(SpB)],
//    computed on the fly from prior layers' partial buffers (no races).
//  - Per block (rg,b,p): stage E' -> LDS; compute Ts (64c) + Tr (its 8 r)
//    via MFMA into swizzled LDS (k_T absorbed, ~16% MFMA overhead); then
//    edge: per r, h-frags from LDS shared across nt=2 d-tiles (a-build
//    VALU/MFMA halved vs v13), W2 ladder bv[2][8] hoisted + in-loop asm pin
//    (live across backedge -> not re-derivable), arc blend, c-sum, store.

#define NB 32
#define NN 64
#define DD 128
#define HH 256

typedef __attribute__((ext_vector_type(4))) float f32x4;
typedef __attribute__((ext_vector_type(8))) _Float16 f16x8;

__device__ __forceinline__ uint64_t cvt4h(f32x4 v) {
  union { _Float16 h[4]; uint64_t u; } x;
  x.h[0] = (_Float16)v[0]; x.h[1] = (_Float16)v[1];
  x.h[2] = (_Float16)v[2]; x.h[3] = (_Float16)v[3];
  return x.u;
}

// Fused setup: gather E0 (256 blk) | W1/W2 -> fp16 (192 blk)
__global__ __launch_bounds__(256) void k_setup(const int* __restrict__ x,
                                               const float* __restrict__ table,
                                               float* __restrict__ E0,
                                               const float* __restrict__ W1_0,
                                               const float* __restrict__ W1_1,
                                               const float* __restrict__ W2_0,
                                               const float* __restrict__ W2_1,
                                               _Float16* __restrict__ W1fp,
                                               _Float16* __restrict__ W2fp) {
  int bid = blockIdx.x, t = threadIdx.x;
  if (bid < 256) {
    int i = bid * 256 + t;
    int node = i >> 5;
    ((f32x4*)E0)[i] = ((const f32x4*)table)[(size_t)x[node] * 32 + (i & 31)];
  } else {
    int tid = (bid - 256) * 256 + t;     // 49152 f32x4 chunks
    const float* src; uint64_t* dst; int off;
    if (tid < 32768) {
      src = (tid < 16384) ? W1_0 : W1_1;
      off = tid & 16383;
      dst = (uint64_t*)W1fp + (tid >> 14) * 16384 + off;
    } else {
      int t2 = tid - 32768;
      src = (t2 < 8192) ? W2_0 : W2_1;
      off = t2 & 8191;
      dst = (uint64_t*)W2fp + (t2 >> 13) * 8192 + off;
    }
    *dst = cvt4h(((const f32x4*)src)[off]);
  }
}

// k_fused<NSP,NR>: grid (NR==8 ? 8 : 1, 32, 2) = (rg, b, p).
// NSP = how many prior Sp generations to fold into E'. NR = r's per block.
template <int NSP, int NR>
__global__ __launch_bounds__(256) void k_fused(
    const float* __restrict__ E0,
    const float* __restrict__ spA,
    const float* __restrict__ spB,
    float* __restrict__ spOut,
    const _Float16* __restrict__ W1fp,
    const _Float16* __restrict__ W2fp,
    const float* __restrict__ b1_0, const float* __restrict__ b1_1,
    const float* __restrict__ b2_0, const float* __restrict__ b2_1,
    const int* __restrict__ arcs) {
  __shared__ char lds[53248];
  char* Els = lds;            // [64 node][256 B]  E' f16, row-swizzled
  char* Tsl = lds + 16384;    // [64 c][512 B]     Ts_p f16, row-swizzled
  char* Trl = lds + 49152;    // [8 lr][512 B]     Tr_p f16 (+b1), row-swizzled

  int t = threadIdx.x;
  int rg = blockIdx.x, b = blockIdx.y, p = blockIdx.z;
  int rbase = rg * 8;
  int lane = t & 63, w = t >> 6, col = lane & 15, khi = lane >> 4;
  const f32x4 z4 = {0.f, 0.f, 0.f, 0.f};

  // ---- stage E' = E0 [+ SpA sums] [+ SpB sums] -> Els (f16, swizzled) ----
  {
    const f32x4* e0 = (const f32x4*)(E0 + (size_t)b * NN * DD);
    const f32x4* a0 = (const f32x4*)(spA + (size_t)b * NN * DD);
    const f32x4* a1 = (const f32x4*)(spA + (size_t)(NB + b) * NN * DD);
    const f32x4* c0 = (const f32x4*)(spB + (size_t)b * NN * DD);
    const f32x4* c1 = (const f32x4*)(spB + (size_t)(NB + b) * NN * DD);
#pragma unroll
    for (int ii = 0; ii < 8; ++ii) {
      int idx = ii * 256 + t;          // f32x4 chunk: node=idx>>5, ck=idx&31
      f32x4 v = e0[idx];
      if (NSP >= 1) v += a0[idx] + a1[idx];
      if (NSP >= 2) v += c0[idx] + c1[idx];
      int node = idx >> 5, ck = idx & 31;
      *(uint64_t*)(Els + node * 256 + ((ck * 8) ^ ((node & 7) << 4))) = cvt4h(v);
    }
  }
  __syncthreads();

  // ---- T-GEMM: Ts = E' @ W1s_p^T (all 64 c); Tr = E' @ W1r_p^T + b1 (8 r) ----
  const _Float16* Wq = W1fp + p * 65536;     // [256 h][256 in]
  const float* b1p = p ? b1_1 : b1_0;
  int eswz = (col & 7) << 4;

#pragma unroll
  for (int nth = 0; nth < 2; ++nth) {        // Ts, two N-halves per wave
    f16x8 bfr[2][4];
#pragma unroll
    for (int nt = 0; nt < 2; ++nt) {
      int h = w * 64 + nth * 32 + nt * 16 + col;
#pragma unroll
      for (int ks = 0; ks < 4; ++ks)
        bfr[nt][ks] = *(const f16x8*)(Wq + h * 256 + ks * 32 + khi * 8);
    }
    f32x4 tacc[4][2];
#pragma unroll
    for (int mt = 0; mt < 4; ++mt) { tacc[mt][0] = z4; tacc[mt][1] = z4; }
#pragma unroll
    for (int ks = 0; ks < 4; ++ks) {
      f16x8 a[4];
#pragma unroll
      for (int mt = 0; mt < 4; ++mt)
        a[mt] = *(const f16x8*)(Els + (mt * 16 + col) * 256 +
                                ((ks * 64 + khi * 16) ^ eswz));
#pragma unroll
      for (int mt = 0; mt < 4; ++mt) {
        tacc[mt][0] = __builtin_amdgcn_mfma_f32_16x16x32_f16(a[mt], bfr[0][ks],
                                                             tacc[mt][0], 0, 0, 0);
        tacc[mt][1] = __builtin_amdgcn_mfma_f32_16x16x32_f16(a[mt], bfr[1][ks],
                                                             tacc[mt][1], 0, 0, 0);
      }
    }
#pragma unroll
    for (int mt = 0; mt < 4; ++mt)
#pragma unroll
      for (int nt = 0; nt < 2; ++nt) {
        int h = w * 64 + nth * 32 + nt * 16 + col;
#pragma unroll
        for (int j = 0; j < 4; ++j) {
          int c = mt * 16 + khi * 4 + j;
          *(_Float16*)(Tsl + c * 512 + ((h * 2) ^ ((c & 7) << 4))) =
              (_Float16)tacc[mt][nt][j];
        }
      }
  }
  {  // Tr: one mt-tile covering rows rbase..rbase+7
    int mt_t = (NR == 1) ? 0 : (rg >> 1);
    int sel = (NR == 1) ? 0 : (rg & 1);
#pragma unroll
    for (int nth = 0; nth < 2; ++nth) {
      f16x8 bfr[2][4];
#pragma unroll
      for (int nt = 0; nt < 2; ++nt) {
        int h = w * 64 + nth * 32 + nt * 16 + col;
#pragma unroll
        for (int ks = 0; ks < 4; ++ks)
          bfr[nt][ks] = *(const f16x8*)(Wq + h * 256 + 128 + ks * 32 + khi * 8);
      }
      f32x4 tacc[2] = {z4, z4};
#pragma unroll
      for (int ks = 0; ks < 4; ++ks) {
        f16x8 a = *(const f16x8*)(Els + (mt_t * 16 + col) * 256 +
                                  ((ks * 64 + khi * 16) ^ eswz));
        tacc[0] = __builtin_amdgcn_mfma_f32_16x16x32_f16(a, bfr[0][ks], tacc[0], 0, 0, 0);
        tacc[1] = __builtin_amdgcn_mfma_f32_16x16x32_f16(a, bfr[1][ks], tacc[1], 0, 0, 0);
      }
      if ((khi >> 1) == sel) {
#pragma unroll
        for (int nt = 0; nt < 2; ++nt) {
          int h = w * 64 + nth * 32 + nt * 16 + col;
          float bb = b1p[h];
#pragma unroll
          for (int j = 0; j < 4; ++j) {
            int lr = (khi & 1) * 4 + j;
            *(_Float16*)(Trl + lr * 512 + ((h * 2) ^ ((lr & 7) << 4))) =
                (_Float16)(tacc[nt][j] + bb);
          }
        }
      }
    }
  }
  __syncthreads();

  // ---- edge: per r, h = relu(Ts + Tr[r]) from LDS, MFMA vs hoisted W2 ----
  int d0 = w * 32 + col;
  const _Float16* W2p = W2fp + p * 32768;
  f16x8 bv[2][8];
#pragma unroll
  for (int nt = 0; nt < 2; ++nt)
#pragma unroll
    for (int ks = 0; ks < 8; ++ks)
      bv[nt][ks] = *(const f16x8*)(W2p + (d0 + nt * 16) * 256 + ks * 32 + khi * 8);
  const float* b2p = p ? b2_1 : b2_0;
  float b2v[2] = {b2p[d0], b2p[d0 + 16]};
  const char* tsb = Tsl + col * 512;

#pragma unroll 1
  for (int r = 0; r < NR; ++r) {
    // residency pin: bv live across the backedge, redefined by opaque asm
    asm volatile("" : "+v"(bv[0][0]), "+v"(bv[0][1]), "+v"(bv[0][2]), "+v"(bv[0][3]),
                      "+v"(bv[0][4]), "+v"(bv[0][5]), "+v"(bv[0][6]), "+v"(bv[0][7]),
                      "+v"(bv[1][0]), "+v"(bv[1][1]), "+v"(bv[1][2]), "+v"(bv[1][3]),
                      "+v"(bv[1][4]), "+v"(bv[1][5]), "+v"(bv[1][6]), "+v"(bv[1][7]));
    f32x4 acc[4][2];
#pragma unroll
    for (int mt = 0; mt < 4; ++mt) { acc[mt][0] = z4; acc[mt][1] = z4; }
#pragma unroll
    for (int ks = 0; ks < 8; ++ks) {
      f16x8 trv = *(const f16x8*)(Trl + r * 512 +
                                  ((ks * 64 + khi * 16) ^ ((r & 7) << 4)));
#pragma unroll
      for (int mt = 0; mt < 4; ++mt) {
        f16x8 ts = *(const f16x8*)(tsb + mt * 8192 + ((ks * 64 + khi * 16) ^ eswz));
        f16x8 zv = {};
        f16x8 a = __builtin_elementwise_max(ts + trv, zv);
        acc[mt][0] = __builtin_amdgcn_mfma_f32_16x16x32_f16(a, bv[0][ks],
                                                            acc[mt][0], 0, 0, 0);
        acc[mt][1] = __builtin_amdgcn_mfma_f32_16x16x32_f16(a, bv[1][ks],
                                                            acc[mt][1], 0, 0, 0);
      }
    }
    int rr = rbase + r;
    const int* arow = arcs + ((size_t)(b * NN + rr)) * NN;
    float s0 = 0.f, s1 = 0.f;
#pragma unroll
    for (int mt = 0; mt < 4; ++mt) {
      const int4 av = *(const int4*)(arow + mt * 16 + khi * 4);
#pragma unroll
      for (int j = 0; j < 4; ++j) {
        int ai = (j == 0) ? av.x : (j == 1) ? av.y : (j == 2) ? av.z : av.w;
        float wgt = p ? (float)ai : 1.0f - (float)ai;
        s0 = fmaf(wgt, fmaxf(acc[mt][0][j] + b2v[0], 0.f), s0);
        s1 = fmaf(wgt, fmaxf(acc[mt][1][j] + b2v[1], 0.f), s1);
      }
    }
    s0 += __shfl_xor(s0, 16); s0 += __shfl_xor(s0, 32);
    s1 += __shfl_xor(s1, 16); s1 += __shfl_xor(s1, 32);
    if (khi == 0) {
      if (NR == 1) {
        float* o = spOut + (size_t)(p * NB + b) * DD;
        o[d0] = s0; o[d0 + 16] = s1;
      } else {
        float* o = spOut + ((size_t)(p * NB + b) * NN + rr) * DD;
        o[d0] = s0; o[d0 + 16] = s1;
      }
    }
  }
}

// out[b][d] = E0[b][0][d] + SpA[0..1][b][0][d] + SpB[0..1][b][0][d] + SpC[0..1][b][d]
__global__ __launch_bounds__(256) void k_out(const float* __restrict__ E0,
                                             const float* __restrict__ spA,
                                             const float* __restrict__ spB,
                                             const float* __restrict__ spC,
                                             float* __restrict__ out) {
  int i = blockIdx.x * 256 + threadIdx.x;      // 4096
  int b = i >> 7, d = i & 127;
  float acc = E0[(size_t)b * NN * DD + d];
  acc += spA[(size_t)b * NN * DD + d] + spA[(size_t)(NB + b) * NN * DD + d];
  acc += spB[(size_t)b * NN * DD + d] + spB[(size_t)(NB + b) * NN * DD + d];
  acc += spC[(size_t)b * DD + d] + spC[(size_t)(NB + b) * DD + d];
  out[i] = acc;
}

extern "C" void kernel_launch(void* const* d_in, const int* in_sizes, int n_in,
                              void* d_out, int out_size, void* d_ws, size_t ws_size,
                              hipStream_t stream) {
  const int* x       = (const int*)d_in[0];
  const int* arcs    = (const int*)d_in[1];
  const float* table = (const float*)d_in[3];
  const float* W1_0  = (const float*)d_in[4];
  const float* b1_0  = (const float*)d_in[5];
  const float* W2_0  = (const float*)d_in[6];
  const float* b2_0  = (const float*)d_in[7];
  const float* W1_1  = (const float*)d_in[8];
  const float* b1_1  = (const float*)d_in[9];
  const float* W2_1  = (const float*)d_in[10];
  const float* b2_1  = (const float*)d_in[11];
  float* out = (float*)d_out;

  char* ws = (char*)d_ws;
  float* E0        = (float*)ws;                                   // 1 MB
  _Float16* W1fp   = (_Float16*)(ws + (1u << 20));                 // 256 KB
  _Float16* W2fp   = (_Float16*)(ws + (1u << 20) + (256u << 10));  // 128 KB
  float* SpA       = (float*)(ws + (2u << 20));                    // 2 MB
  float* SpB       = (float*)(ws + (4u << 20));                    // 2 MB
  float* SpC       = (float*)(ws + (6u << 20));                    // 32 KB

  k_setup<<<448, 256, 0, stream>>>(x, table, E0, W1_0, W1_1, W2_0, W2_1,
                                   W1fp, W2fp);
  k_fused<0, 8><<<dim3(8, 32, 2), 256, 0, stream>>>(
      E0, E0, E0, SpA, W1fp, W2fp, b1_0, b1_1, b2_0, b2_1, arcs);
  k_fused<1, 8><<<dim3(8, 32, 2), 256, 0, stream>>>(
      E0, SpA, E0, SpB, W1fp, W2fp, b1_0, b1_1, b2_0, b2_1, arcs);
  k_fused<2, 1><<<dim3(1, 32, 2), 256, 0, stream>>>(
      E0, SpA, SpB, SpC, W1fp, W2fp, b1_0, b1_1, b2_0, b2_1, arcs);
  k_out<<<16, 256, 0, stream>>>(E0, SpA, SpB, SpC, out);
}